// Round 4
// baseline (1075.804 us; speedup 1.0000x reference)
//
#include <hip/hip_runtime.h>
#include <hip/hip_bf16.h>
#include <math.h>

// Problem constants (fixed by the reference file).
constexpr int N_NODES = 100000;
constexpr int N_EDGES = 3200000;
constexpr int F_IN    = 512;
constexpr int HID     = 16;   // HIDDEN == N_CLASSES == 16

constexpr int NPAD = 100352;  // N_NODES rounded up (words)

// Binning parameters: bucket = dst >> 8 (256 nodes/bucket)
constexpr int B_BITS = 8;
constexpr int NPB    = 1 << B_BITS;                    // 256 nodes per bucket
constexpr int NBKT   = (N_NODES + NPB - 1) / NPB;      // 391 buckets
constexpr int SBLK   = 400;                            // scatter blocks
constexpr int CHUNK  = N_EDGES / SBLK;                 // 8000 edges/block (exact)

// ---------------------------------------------------------------------------
// K1: per-block LDS histogram of dst-buckets -> global bucket counts.
__global__ __launch_bounds__(1024) void bin_count_kernel(const int* __restrict__ dst,
                                                         int* __restrict__ gcnt) {
    __shared__ int cnt[NBKT];
    const int tid = threadIdx.x;
    for (int t = tid; t < NBKT; t += 1024) cnt[t] = 0;
    __syncthreads();
    const int base = blockIdx.x * CHUNK;
    for (int i = tid; i < CHUNK; i += 1024)
        atomicAdd(&cnt[dst[base + i] >> B_BITS], 1);
    __syncthreads();
    for (int t = tid; t < NBKT; t += 1024)
        if (cnt[t]) atomicAdd(&gcnt[t], cnt[t]);
}

// ---------------------------------------------------------------------------
// K2: scan 391 bucket counts -> bucket base offsets (+ cursor copy). 1 block.
__global__ __launch_bounds__(512) void bucket_scan_kernel(const int* __restrict__ gcnt,
                                                          int* __restrict__ bbase,
                                                          int* __restrict__ gcur) {
    __shared__ int s[512];
    const int tid = threadIdx.x;
    s[tid] = (tid < NBKT) ? gcnt[tid] : 0;
    __syncthreads();
    for (int off = 1; off < 512; off <<= 1) {
        int v = (tid >= off) ? s[tid - off] : 0;
        __syncthreads();
        s[tid] += v;
        __syncthreads();
    }
    int excl = (tid == 0) ? 0 : s[tid - 1];
    if (tid <= NBKT) bbase[tid] = excl;
    if (tid <  NBKT) gcur[tid]  = excl;
}

// ---------------------------------------------------------------------------
// K3: scatter edges into bucket-grouped array (writes L2-localized),
// packed as (local_dst<<24 | src). This IS the edge structure both pulls
// consume — no CSR needed.
__global__ __launch_bounds__(1024) void bin_scatter_kernel(const int* __restrict__ src,
                                                           const int* __restrict__ dst,
                                                           int* __restrict__ gcur,
                                                           unsigned int* __restrict__ binned) {
    __shared__ int cnt[NBKT];
    __shared__ int cur[NBKT];
    const int tid = threadIdx.x;
    for (int t = tid; t < NBKT; t += 1024) cnt[t] = 0;
    __syncthreads();
    const int base = blockIdx.x * CHUNK;
    for (int i = tid; i < CHUNK; i += 1024)
        atomicAdd(&cnt[dst[base + i] >> B_BITS], 1);
    __syncthreads();
    for (int t = tid; t < NBKT; t += 1024)
        cur[t] = cnt[t] ? atomicAdd(&gcur[t], cnt[t]) : 0;
    __syncthreads();
    for (int i = tid; i < CHUNK; i += 1024) {
        int d = dst[base + i];
        int b = d >> B_BITS;
        int pos = atomicAdd(&cur[b], 1);
        binned[pos] = ((unsigned)(d & (NPB - 1)) << 24) | (unsigned)src[base + i];
    }
}

// ---------------------------------------------------------------------------
// K4: per-bucket degree histogram -> dinv. Coalesced streaming read of the
// bucket's binned edges; replaces the full CSR-build kernel.
__global__ __launch_bounds__(1024) void deg_bucket_kernel(const unsigned int* __restrict__ binned,
                                                          const int* __restrict__ bbase,
                                                          float* __restrict__ dinv) {
    __shared__ int deg[NPB];
    const int tid = threadIdx.x;
    const int b = blockIdx.x;
    if (tid < NPB) deg[tid] = 0;
    __syncthreads();
    const int e0 = bbase[b], e1 = bbase[b + 1];
    for (int e = e0 + tid; e < e1; e += 1024)
        atomicAdd(&deg[binned[e] >> 24], 1);
    __syncthreads();
    if (tid < NPB) {
        int node = (b << B_BITS) + tid;
        if (node < N_NODES) dinv[node] = rsqrtf((float)deg[tid] + 1.0f);
    }
}

// ---------------------------------------------------------------------------
// K5: GEMM1  h = x @ W1 ; writes hh = h*dinv and agg1 = h*dinv^2 + b1.
// x-tile staged via global_load_lds width=16; 4 k-groups rotated to disjoint
// bank-quads. (Unchanged from R3 — isolate the pull-path delta this round.)
__global__ __launch_bounds__(256) void gemm1_kernel(const float* __restrict__ x,
                                                    const float* __restrict__ W1,
                                                    const float* __restrict__ b1,
                                                    const float* __restrict__ dinv,
                                                    float* __restrict__ hh,
                                                    float* __restrict__ agg1) {
    __shared__ float xs[16 * 512];          // 32 KB x-tile
    __shared__ float w1s[3 * 2064 + 2048];  // 32.96 KB, group base g*2064 -> banks {j, j+16}
    const int tid = threadIdx.x;

    const float* gsrc = x + (size_t)blockIdx.x * 16 * F_IN;
    #pragma unroll
    for (int r = 0; r < 8; ++r) {
        int off = (r * 256 + tid) * 4;
        __builtin_amdgcn_global_load_lds(
            (const __attribute__((address_space(1))) void*)(gsrc + off),
            (__attribute__((address_space(3))) void*)(xs + off), 16, 0, 0);
    }
    for (int i = tid * 4; i < F_IN * HID; i += 256 * 4) {
        float4 v = *(const float4*)(W1 + i);
        int k = i >> 4, jw = i & 15;
        *(float4*)(w1s + (k >> 7) * 2064 + (k & 127) * 16 + jw) = v;
    }
    __syncthreads();

    const int wave = tid >> 6;
    const int lane = tid & 63;
    const int g = lane >> 4;
    const int j = lane & 15;
    const int node0 = blockIdx.x * 16 + wave * 4;

    const float* xr0 = xs + (wave * 4 + 0) * F_IN + g * 128;
    const float* xr1 = xs + (wave * 4 + 1) * F_IN + g * 128;
    const float* xr2 = xs + (wave * 4 + 2) * F_IN + g * 128;
    const float* xr3 = xs + (wave * 4 + 3) * F_IN + g * 128;
    const float* wg = w1s + g * 2064 + j;

    float acc0 = 0.f, acc1 = 0.f, acc2 = 0.f, acc3 = 0.f;
    const int rot = g << 1;
    #pragma unroll 4
    for (int t = 0; t < 32; ++t) {
        const int kk = ((t + rot) & 31) << 2;
        float4 a0 = *(const float4*)(xr0 + kk);
        float4 a1 = *(const float4*)(xr1 + kk);
        float4 a2 = *(const float4*)(xr2 + kk);
        float4 a3 = *(const float4*)(xr3 + kk);
        const float* wp = wg + kk * 16;
        float w0 = wp[0], w1v = wp[16], w2v = wp[32], w3v = wp[48];
        acc0 += a0.x * w0 + a0.y * w1v + a0.z * w2v + a0.w * w3v;
        acc1 += a1.x * w0 + a1.y * w1v + a1.z * w2v + a1.w * w3v;
        acc2 += a2.x * w0 + a2.y * w1v + a2.z * w2v + a2.w * w3v;
        acc3 += a3.x * w0 + a3.y * w1v + a3.z * w2v + a3.w * w3v;
    }
    acc0 += __shfl_xor(acc0, 16); acc0 += __shfl_xor(acc0, 32);
    acc1 += __shfl_xor(acc1, 16); acc1 += __shfl_xor(acc1, 32);
    acc2 += __shfl_xor(acc2, 16); acc2 += __shfl_xor(acc2, 32);
    acc3 += __shfl_xor(acc3, 16); acc3 += __shfl_xor(acc3, 32);

    if (g == 0) {
        float b1j = b1[j];
        float dv, hv;
        size_t o;
        dv = dinv[node0 + 0]; hv = acc0 * dv; o = (size_t)(node0 + 0) * 16 + j;
        hh[o] = hv; agg1[o] = hv * dv + b1j;
        dv = dinv[node0 + 1]; hv = acc1 * dv; o = (size_t)(node0 + 1) * 16 + j;
        hh[o] = hv; agg1[o] = hv * dv + b1j;
        dv = dinv[node0 + 2]; hv = acc2 * dv; o = (size_t)(node0 + 2) * 16 + j;
        hh[o] = hv; agg1[o] = hv * dv + b1j;
        dv = dinv[node0 + 3]; hv = acc3 * dv; o = (size_t)(node0 + 3) * 16 + j;
        hh[o] = hv; agg1[o] = hv * dv + b1j;
    }
}

// ---------------------------------------------------------------------------
// K6/K8: NEW edge-parallel bucket-local pull. One block per bucket; LDS
// accumulator (256 nodes x 16 feats = 16 KB); threads stream the bucket's
// edges (coalesced binned reads), gather hh[src] (64 B line per edge, L2-hot
// 6.4 MB table), atomicAdd into LDS, then one coalesced RMW of agg:
// agg[node] += dinv[node] * acc[node]. No CSR, no per-node loops, perfect
// load balance, zero global float atomics.
__global__ __launch_bounds__(1024) void pull_bucket_kernel(const unsigned int* __restrict__ binned,
                                                           const int* __restrict__ bbase,
                                                           const float* __restrict__ hh,
                                                           const float* __restrict__ dinv,
                                                           float* __restrict__ agg) {
    __shared__ float acc[NPB * 16];  // 16 KB
    const int tid = threadIdx.x;
    const int b = blockIdx.x;
    const int j = tid & 15;
    const int slot = tid >> 4;       // 0..63
    for (int i = tid; i < NPB * 16; i += 1024) acc[i] = 0.f;
    __syncthreads();
    const int e0 = bbase[b], e1 = bbase[b + 1];
    for (int e = e0 + slot; e < e1; e += 64) {
        unsigned int v = binned[e];
        int s  = (int)(v & 0xFFFFFFu);
        int ld = (int)(v >> 24);
        float val = hh[(s << 4) + j];
        atomicAdd(&acc[(ld << 4) + j], val);
    }
    __syncthreads();
    const int node0 = b << B_BITS;
    for (int i = tid; i < NPB * 16; i += 1024) {
        int node = node0 + (i >> 4);
        if (node < N_NODES) {
            size_t o = (size_t)node * 16 + (i & 15);
            agg[o] += dinv[node] * acc[i];
        }
    }
}

// ---------------------------------------------------------------------------
// K7: layer 2 — h1 = relu(agg1); h2 = h1 @ W2; hh2 = h2*dinv; agg2 = h2*dinv^2 + b2
__global__ __launch_bounds__(256) void layer2_kernel(const float* __restrict__ agg1,
                                                     const float* __restrict__ W2,
                                                     const float* __restrict__ b2,
                                                     const float* __restrict__ dinv,
                                                     float* __restrict__ hh2,
                                                     float* __restrict__ agg2) {
    __shared__ float w2s[256];
    __shared__ float b2s[16];
    const int tid = threadIdx.x;
    w2s[tid] = W2[tid];
    if (tid < 16) b2s[tid] = b2[tid];
    __syncthreads();
    int i = blockIdx.x * 256 + tid;
    if (i >= N_NODES) return;
    float v[16];
    const float4* ar = (const float4*)(agg1 + (size_t)i * 16);
    float4 r0 = ar[0], r1 = ar[1], r2 = ar[2], r3 = ar[3];
    v[0]=r0.x; v[1]=r0.y; v[2]=r0.z; v[3]=r0.w;
    v[4]=r1.x; v[5]=r1.y; v[6]=r1.z; v[7]=r1.w;
    v[8]=r2.x; v[9]=r2.y; v[10]=r2.z; v[11]=r2.w;
    v[12]=r3.x; v[13]=r3.y; v[14]=r3.z; v[15]=r3.w;
    #pragma unroll
    for (int k = 0; k < 16; ++k) v[k] = fmaxf(v[k], 0.f);
    float dv = dinv[i], dv2 = dv * dv;
    float o[16];
    #pragma unroll
    for (int jj = 0; jj < 16; ++jj) {
        float s = 0.f;
        #pragma unroll
        for (int k = 0; k < 16; ++k) s += v[k] * w2s[k * 16 + jj];
        o[jj] = s;
    }
    float4* ho = (float4*)(hh2 + (size_t)i * 16);
    float4* ao = (float4*)(agg2 + (size_t)i * 16);
    ho[0] = make_float4(o[0]*dv,  o[1]*dv,  o[2]*dv,  o[3]*dv);
    ho[1] = make_float4(o[4]*dv,  o[5]*dv,  o[6]*dv,  o[7]*dv);
    ho[2] = make_float4(o[8]*dv,  o[9]*dv,  o[10]*dv, o[11]*dv);
    ho[3] = make_float4(o[12]*dv, o[13]*dv, o[14]*dv, o[15]*dv);
    ao[0] = make_float4(o[0]*dv2+b2s[0],  o[1]*dv2+b2s[1],  o[2]*dv2+b2s[2],  o[3]*dv2+b2s[3]);
    ao[1] = make_float4(o[4]*dv2+b2s[4],  o[5]*dv2+b2s[5],  o[6]*dv2+b2s[6],  o[7]*dv2+b2s[7]);
    ao[2] = make_float4(o[8]*dv2+b2s[8],  o[9]*dv2+b2s[9],  o[10]*dv2+b2s[10],o[11]*dv2+b2s[11]);
    ao[3] = make_float4(o[12]*dv2+b2s[12],o[13]*dv2+b2s[13],o[14]*dv2+b2s[14],o[15]*dv2+b2s[15]);
}

// ---------------------------------------------------------------------------
// K9: log_softmax over 16 classes
__global__ __launch_bounds__(256) void lsm_kernel(const float* __restrict__ agg2,
                                                  float* __restrict__ out) {
    int i = blockIdx.x * 256 + threadIdx.x;
    if (i >= N_NODES) return;
    float v[16];
    const float4* ar = (const float4*)(agg2 + (size_t)i * 16);
    float4 r0 = ar[0], r1 = ar[1], r2 = ar[2], r3 = ar[3];
    v[0]=r0.x; v[1]=r0.y; v[2]=r0.z; v[3]=r0.w;
    v[4]=r1.x; v[5]=r1.y; v[6]=r1.z; v[7]=r1.w;
    v[8]=r2.x; v[9]=r2.y; v[10]=r2.z; v[11]=r2.w;
    v[12]=r3.x; v[13]=r3.y; v[14]=r3.z; v[15]=r3.w;
    float m = v[0];
    #pragma unroll
    for (int k = 1; k < 16; ++k) m = fmaxf(m, v[k]);
    float ssum = 0.f;
    #pragma unroll
    for (int k = 0; k < 16; ++k) ssum += expf(v[k] - m);
    float l = m + logf(ssum);
    float4* oo = (float4*)(out + (size_t)i * 16);
    oo[0] = make_float4(v[0]-l, v[1]-l, v[2]-l, v[3]-l);
    oo[1] = make_float4(v[4]-l, v[5]-l, v[6]-l, v[7]-l);
    oo[2] = make_float4(v[8]-l, v[9]-l, v[10]-l, v[11]-l);
    oo[3] = make_float4(v[12]-l, v[13]-l, v[14]-l, v[15]-l);
}

// ---------------------------------------------------------------------------
extern "C" void kernel_launch(void* const* d_in, const int* in_sizes, int n_in,
                              void* d_out, int out_size, void* d_ws, size_t ws_size,
                              hipStream_t stream) {
    const float* x    = (const float*)d_in[0];
    const float* W1   = (const float*)d_in[1];
    const float* b1   = (const float*)d_in[2];
    const float* W2   = (const float*)d_in[3];
    const float* b2   = (const float*)d_in[4];
    const int*   ei   = (const int*)d_in[5];
    const int*   src  = ei;             // edge_index[0]
    const int*   dst  = ei + N_EDGES;   // edge_index[1]
    float* out = (float*)d_out;

    // workspace layout (4-byte words); total ~39 MB
    int*   wsi  = (int*)d_ws;
    float* wsf  = (float*)d_ws;
    int*   gcnt  = wsi;                        // [NBKT]
    int*   bbase = wsi + 512;                  // [NBKT+1]
    int*   gcur  = wsi + 1024;                 // [NBKT]
    float* dinv  = wsf + 2048;                 // [NPAD]
    unsigned int* binned = (unsigned int*)(wsi + 2048 + NPAD);  // [E]
    float* hh    = wsf + 2048 + NPAD + N_EDGES;        // [N*16]
    float* agg1  = hh   + (size_t)N_NODES * 16;        // [N*16]
    float* hh2   = agg1 + (size_t)N_NODES * 16;        // [N*16]
    float* agg2  = hh2  + (size_t)N_NODES * 16;        // [N*16]

    const int NB = (N_NODES + 255) / 256;      // 391
    const int GB = N_NODES / 16;               // 6250 (exact)

    hipMemsetAsync(gcnt, 0, NBKT * sizeof(int), stream);
    bin_count_kernel <<<SBLK, 1024, 0, stream>>>(dst, gcnt);
    bucket_scan_kernel<<<1, 512, 0, stream>>>(gcnt, bbase, gcur);
    bin_scatter_kernel<<<SBLK, 1024, 0, stream>>>(src, dst, gcur, binned);
    deg_bucket_kernel<<<NBKT, 1024, 0, stream>>>(binned, bbase, dinv);
    gemm1_kernel<<<GB, 256, 0, stream>>>(x, W1, b1, dinv, hh, agg1);
    pull_bucket_kernel<<<NBKT, 1024, 0, stream>>>(binned, bbase, hh, dinv, agg1);
    layer2_kernel<<<NB, 256, 0, stream>>>(agg1, W2, b2, dinv, hh2, agg2);
    pull_bucket_kernel<<<NBKT, 1024, 0, stream>>>(binned, bbase, hh2, dinv, agg2);
    lsm_kernel<<<NB, 256, 0, stream>>>(agg2, out);
}

// Round 5
// 492.959 us; speedup vs baseline: 2.1823x; 2.1823x over previous
//
#include <hip/hip_runtime.h>
#include <hip/hip_bf16.h>
#include <math.h>

// Problem constants (fixed by the reference file).
constexpr int N_NODES = 100000;
constexpr int N_EDGES = 3200000;
constexpr int F_IN    = 512;
constexpr int HID     = 16;   // HIDDEN == N_CLASSES == 16

constexpr int NPAD = 100352;  // N_NODES rounded up (words)

// Binning parameters: bucket = dst >> 8 (256 nodes/bucket)
constexpr int B_BITS = 8;
constexpr int NPB    = 1 << B_BITS;                    // 256 nodes per bucket
constexpr int NBKT   = (N_NODES + NPB - 1) / NPB;      // 391 buckets
constexpr int SBLK   = 400;                            // scatter blocks
constexpr int CHUNK  = N_EDGES / SBLK;                 // 8000 edges/block (exact)
constexpr int MAX_BKT_E = 12288;  // mean 8184, sd ~90; 48KB LDS

typedef float f32x4 __attribute__((ext_vector_type(4)));
typedef short bfrag8 __attribute__((ext_vector_type(8)));   // 8 bf16 (4 VGPRs)

__device__ __forceinline__ unsigned short f2bf_rne(float f) {
    unsigned int u = __float_as_uint(f);
    u += 0x7FFFu + ((u >> 16) & 1u);   // round-to-nearest-even
    return (unsigned short)(u >> 16);
}

// ---------------------------------------------------------------------------
// K1: per-block LDS histogram of dst-buckets -> global bucket counts.
__global__ __launch_bounds__(1024) void bin_count_kernel(const int* __restrict__ dst,
                                                         int* __restrict__ gcnt) {
    __shared__ int cnt[NBKT];
    const int tid = threadIdx.x;
    for (int t = tid; t < NBKT; t += 1024) cnt[t] = 0;
    __syncthreads();
    const int base = blockIdx.x * CHUNK;
    for (int i = tid; i < CHUNK; i += 1024)
        atomicAdd(&cnt[dst[base + i] >> B_BITS], 1);
    __syncthreads();
    for (int t = tid; t < NBKT; t += 1024)
        if (cnt[t]) atomicAdd(&gcnt[t], cnt[t]);
}

// ---------------------------------------------------------------------------
// K2: scan 391 bucket counts -> bucket base offsets (+ cursor copy). 1 block.
__global__ __launch_bounds__(512) void bucket_scan_kernel(const int* __restrict__ gcnt,
                                                          int* __restrict__ bbase,
                                                          int* __restrict__ gcur) {
    __shared__ int s[512];
    const int tid = threadIdx.x;
    s[tid] = (tid < NBKT) ? gcnt[tid] : 0;
    __syncthreads();
    for (int off = 1; off < 512; off <<= 1) {
        int v = (tid >= off) ? s[tid - off] : 0;
        __syncthreads();
        s[tid] += v;
        __syncthreads();
    }
    int excl = (tid == 0) ? 0 : s[tid - 1];
    if (tid <= NBKT) bbase[tid] = excl;
    if (tid <  NBKT) gcur[tid]  = excl;
}

// ---------------------------------------------------------------------------
// K3: scatter edges into bucket-grouped array (writes L2-localized),
// packed as (local_dst<<24 | src).
__global__ __launch_bounds__(1024) void bin_scatter_kernel(const int* __restrict__ src,
                                                           const int* __restrict__ dst,
                                                           int* __restrict__ gcur,
                                                           unsigned int* __restrict__ binned) {
    __shared__ int cnt[NBKT];
    __shared__ int cur[NBKT];
    const int tid = threadIdx.x;
    for (int t = tid; t < NBKT; t += 1024) cnt[t] = 0;
    __syncthreads();
    const int base = blockIdx.x * CHUNK;
    for (int i = tid; i < CHUNK; i += 1024)
        atomicAdd(&cnt[dst[base + i] >> B_BITS], 1);
    __syncthreads();
    for (int t = tid; t < NBKT; t += 1024)
        cur[t] = cnt[t] ? atomicAdd(&gcur[t], cnt[t]) : 0;
    __syncthreads();
    for (int i = tid; i < CHUNK; i += 1024) {
        int d = dst[base + i];
        int b = d >> B_BITS;
        int pos = atomicAdd(&cur[b], 1);
        binned[pos] = ((unsigned)(d & (NPB - 1)) << 24) | (unsigned)src[base + i];
    }
}

// ---------------------------------------------------------------------------
// K4: one block per bucket: LDS-local CSR build + deg/dinv/row emission.
// (R3 proven version.)
__global__ __launch_bounds__(1024) void csr_bucket_kernel(const unsigned int* __restrict__ binned,
                                                          const int* __restrict__ bbase,
                                                          int* __restrict__ row,
                                                          int* __restrict__ csr,
                                                          float* __restrict__ dinv) {
    __shared__ unsigned int eb[MAX_BKT_E];
    __shared__ int deg[NPB];
    __shared__ int pre[NPB];
    __shared__ int cur[NPB];
    const int tid = threadIdx.x;
    const int b = blockIdx.x;
    const int e0 = bbase[b];
    int ne = bbase[b + 1] - e0;
    if (ne > MAX_BKT_E) ne = MAX_BKT_E;  // safety (statistically impossible)

    if (tid < NPB) deg[tid] = 0;
    for (int i = tid; i < ne; i += 1024) eb[i] = binned[e0 + i];
    __syncthreads();
    for (int i = tid; i < ne; i += 1024)
        atomicAdd(&deg[eb[i] >> 24], 1);
    __syncthreads();
    if (tid < NPB) pre[tid] = deg[tid];
    __syncthreads();
    for (int off = 1; off < NPB; off <<= 1) {
        int v = 0;
        if (tid < NPB && tid >= off) v = pre[tid - off];
        __syncthreads();
        if (tid < NPB) pre[tid] += v;
        __syncthreads();
    }
    if (tid < NPB) {
        int excl = (tid == 0) ? 0 : pre[tid - 1];
        int g = e0 + excl;
        cur[tid] = g;
        int node = b * NPB + tid;
        if (node < N_NODES) {
            row[node] = g;
            dinv[node] = rsqrtf((float)deg[tid] + 1.0f);
        }
    }
    if (b == 0 && tid == 0) row[N_NODES] = N_EDGES;
    __syncthreads();
    for (int i = tid; i < ne; i += 1024) {
        unsigned int v = eb[i];
        int pos = atomicAdd(&cur[v >> 24], 1);
        csr[pos] = (int)(v & 0xFFFFFFu);
    }
}

// ---------------------------------------------------------------------------
// K5a: W1 prep — fp32 [k][n] -> bf16 transposed w1t[n][k]. One block, tiny.
__global__ __launch_bounds__(256) void w1prep_kernel(const float* __restrict__ W1,
                                                     unsigned short* __restrict__ w1t) {
    int i = blockIdx.x * 256 + threadIdx.x;
    if (i < F_IN * HID) {
        int k = i >> 4, n = i & 15;
        w1t[n * F_IN + k] = f2bf_rne(W1[i]);
    }
}

// ---------------------------------------------------------------------------
// K5: GEMM1 via MFMA bf16. Block = 256 (4 waves), 64 nodes/block, 16/wave.
// x-tile fp32 -> bf16 staged in LDS (row stride 520 bf16 spreads A-frag
// granules over banks); all 16 B-frags (W1^T, L2-hot) preloaded to registers;
// K-loop = 16 x (ds_read_b128 A-frag + mfma_f32_16x16x32_bf16).
// C/D layout: col(j)=lane&15, row(node)=quad*4+reg. A: m=lane&15, k=quad*8+i.
__global__ __launch_bounds__(256) void gemm1_kernel(const float* __restrict__ x,
                                                    const unsigned short* __restrict__ w1t,
                                                    const float* __restrict__ b1,
                                                    const float* __restrict__ dinv,
                                                    float* __restrict__ hh,
                                                    float* __restrict__ agg1) {
    __shared__ unsigned short xs[64 * 520];  // 65 KB
    const int tid = threadIdx.x;
    const int node0 = blockIdx.x * 64;

    // stage x (coalesced float4) -> bf16 LDS; clamp OOB rows (stores guarded)
    #pragma unroll
    for (int r = 0; r < 32; ++r) {
        int idx = (r * 256 + tid) * 4;         // element in 64x512 tile
        int ln = idx >> 9;                      // local node
        int k  = idx & 511;
        int gn = node0 + ln; if (gn >= N_NODES) gn = N_NODES - 1;
        float4 v = *(const float4*)(x + (size_t)gn * F_IN + k);
        ushort4 bv;
        bv.x = f2bf_rne(v.x); bv.y = f2bf_rne(v.y);
        bv.z = f2bf_rne(v.z); bv.w = f2bf_rne(v.w);
        *(ushort4*)(xs + ln * 520 + k) = bv;
    }

    const int lane = tid & 63;
    const int wv   = tid >> 6;
    const int m    = lane & 15;   // node-in-tile / feature col (C/D)
    const int quad = lane >> 4;

    // preload all 16 B-frags from global (16 KB table, L2-hot)
    bfrag8 bfr[16];
    const unsigned short* wbase = w1t + m * F_IN + quad * 8;
    #pragma unroll
    for (int t = 0; t < 16; ++t)
        bfr[t] = *(const bfrag8*)(wbase + t * 32);

    __syncthreads();

    f32x4 acc = {0.f, 0.f, 0.f, 0.f};
    const unsigned short* arow = xs + (wv * 16 + m) * 520 + quad * 8;
    #pragma unroll
    for (int t = 0; t < 16; ++t) {
        bfrag8 afr = *(const bfrag8*)(arow + t * 32);
        acc = __builtin_amdgcn_mfma_f32_16x16x32_bf16(afr, bfr[t], acc, 0, 0, 0);
    }

    // epilogue: D[row=quad*4+r][col=m]; hh = h*dinv, agg1 = h*dinv^2 + b1
    const float b1j = b1[m];
    #pragma unroll
    for (int r = 0; r < 4; ++r) {
        int gn = node0 + wv * 16 + quad * 4 + r;
        if (gn < N_NODES) {
            float dv = dinv[gn];
            float hv = acc[r] * dv;
            size_t o = (size_t)gn * 16 + m;
            hh[o] = hv;
            agg1[o] = hv * dv + b1j;
        }
    }
}

// ---------------------------------------------------------------------------
// K6/K8: pull aggregation (R3 proven). agg[i][j] += dinv[i]*sum hh[s][j].
// 16 lanes per node, x4 unroll -> 4 outstanding gathers/wave, 6250 blocks.
__global__ __launch_bounds__(256) void pull_kernel(const float* __restrict__ hh,
                                                   const float* __restrict__ dinv,
                                                   const int* __restrict__ row,
                                                   const int* __restrict__ csr,
                                                   float* __restrict__ agg) {
    int t = blockIdx.x * 256 + threadIdx.x;
    int node = t >> 4;
    int j = t & 15;
    if (node >= N_NODES) return;
    int p = row[node], end = row[node + 1];
    float a0 = 0.f, a1 = 0.f, a2 = 0.f, a3 = 0.f;
    for (; p + 4 <= end; p += 4) {
        int s0 = csr[p], s1 = csr[p + 1], s2 = csr[p + 2], s3 = csr[p + 3];
        a0 += hh[(s0 << 4) + j];
        a1 += hh[(s1 << 4) + j];
        a2 += hh[(s2 << 4) + j];
        a3 += hh[(s3 << 4) + j];
    }
    for (; p < end; ++p) a0 += hh[(csr[p] << 4) + j];
    float acc = (a0 + a1) + (a2 + a3);
    agg[(node << 4) + j] += dinv[node] * acc;
}

// ---------------------------------------------------------------------------
// K7: layer 2 — h1 = relu(agg1); h2 = h1 @ W2; hh2 = h2*dinv; agg2 = h2*dinv^2 + b2
__global__ __launch_bounds__(256) void layer2_kernel(const float* __restrict__ agg1,
                                                     const float* __restrict__ W2,
                                                     const float* __restrict__ b2,
                                                     const float* __restrict__ dinv,
                                                     float* __restrict__ hh2,
                                                     float* __restrict__ agg2) {
    __shared__ float w2s[256];
    __shared__ float b2s[16];
    const int tid = threadIdx.x;
    w2s[tid] = W2[tid];
    if (tid < 16) b2s[tid] = b2[tid];
    __syncthreads();
    int i = blockIdx.x * 256 + tid;
    if (i >= N_NODES) return;
    float v[16];
    const float4* ar = (const float4*)(agg1 + (size_t)i * 16);
    float4 r0 = ar[0], r1 = ar[1], r2 = ar[2], r3 = ar[3];
    v[0]=r0.x; v[1]=r0.y; v[2]=r0.z; v[3]=r0.w;
    v[4]=r1.x; v[5]=r1.y; v[6]=r1.z; v[7]=r1.w;
    v[8]=r2.x; v[9]=r2.y; v[10]=r2.z; v[11]=r2.w;
    v[12]=r3.x; v[13]=r3.y; v[14]=r3.z; v[15]=r3.w;
    #pragma unroll
    for (int k = 0; k < 16; ++k) v[k] = fmaxf(v[k], 0.f);
    float dv = dinv[i], dv2 = dv * dv;
    float o[16];
    #pragma unroll
    for (int jj = 0; jj < 16; ++jj) {
        float s = 0.f;
        #pragma unroll
        for (int k = 0; k < 16; ++k) s += v[k] * w2s[k * 16 + jj];
        o[jj] = s;
    }
    float4* ho = (float4*)(hh2 + (size_t)i * 16);
    float4* ao = (float4*)(agg2 + (size_t)i * 16);
    ho[0] = make_float4(o[0]*dv,  o[1]*dv,  o[2]*dv,  o[3]*dv);
    ho[1] = make_float4(o[4]*dv,  o[5]*dv,  o[6]*dv,  o[7]*dv);
    ho[2] = make_float4(o[8]*dv,  o[9]*dv,  o[10]*dv, o[11]*dv);
    ho[3] = make_float4(o[12]*dv, o[13]*dv, o[14]*dv, o[15]*dv);
    ao[0] = make_float4(o[0]*dv2+b2s[0],  o[1]*dv2+b2s[1],  o[2]*dv2+b2s[2],  o[3]*dv2+b2s[3]);
    ao[1] = make_float4(o[4]*dv2+b2s[4],  o[5]*dv2+b2s[5],  o[6]*dv2+b2s[6],  o[7]*dv2+b2s[7]);
    ao[2] = make_float4(o[8]*dv2+b2s[8],  o[9]*dv2+b2s[9],  o[10]*dv2+b2s[10],o[11]*dv2+b2s[11]);
    ao[3] = make_float4(o[12]*dv2+b2s[12],o[13]*dv2+b2s[13],o[14]*dv2+b2s[14],o[15]*dv2+b2s[15]);
}

// ---------------------------------------------------------------------------
// K9: log_softmax over 16 classes
__global__ __launch_bounds__(256) void lsm_kernel(const float* __restrict__ agg2,
                                                  float* __restrict__ out) {
    int i = blockIdx.x * 256 + threadIdx.x;
    if (i >= N_NODES) return;
    float v[16];
    const float4* ar = (const float4*)(agg2 + (size_t)i * 16);
    float4 r0 = ar[0], r1 = ar[1], r2 = ar[2], r3 = ar[3];
    v[0]=r0.x; v[1]=r0.y; v[2]=r0.z; v[3]=r0.w;
    v[4]=r1.x; v[5]=r1.y; v[6]=r1.z; v[7]=r1.w;
    v[8]=r2.x; v[9]=r2.y; v[10]=r2.z; v[11]=r2.w;
    v[12]=r3.x; v[13]=r3.y; v[14]=r3.z; v[15]=r3.w;
    float m = v[0];
    #pragma unroll
    for (int k = 1; k < 16; ++k) m = fmaxf(m, v[k]);
    float ssum = 0.f;
    #pragma unroll
    for (int k = 0; k < 16; ++k) ssum += expf(v[k] - m);
    float l = m + logf(ssum);
    float4* oo = (float4*)(out + (size_t)i * 16);
    oo[0] = make_float4(v[0]-l, v[1]-l, v[2]-l, v[3]-l);
    oo[1] = make_float4(v[4]-l, v[5]-l, v[6]-l, v[7]-l);
    oo[2] = make_float4(v[8]-l, v[9]-l, v[10]-l, v[11]-l);
    oo[3] = make_float4(v[12]-l, v[13]-l, v[14]-l, v[15]-l);
}

// ---------------------------------------------------------------------------
extern "C" void kernel_launch(void* const* d_in, const int* in_sizes, int n_in,
                              void* d_out, int out_size, void* d_ws, size_t ws_size,
                              hipStream_t stream) {
    const float* x    = (const float*)d_in[0];
    const float* W1   = (const float*)d_in[1];
    const float* b1   = (const float*)d_in[2];
    const float* W2   = (const float*)d_in[3];
    const float* b2   = (const float*)d_in[4];
    const int*   ei   = (const int*)d_in[5];
    const int*   src  = ei;             // edge_index[0]
    const int*   dst  = ei + N_EDGES;   // edge_index[1]
    float* out = (float*)d_out;

    // workspace layout (4-byte words); total ~39.3 MB
    int*   wsi  = (int*)d_ws;
    float* wsf  = (float*)d_ws;
    int*   gcnt  = wsi;                        // [NBKT]
    int*   bbase = wsi + 512;                  // [NBKT+1]
    int*   gcur  = wsi + 1024;                 // [NBKT]
    float* dinv  = wsf + 2048;                 // [NPAD]
    int*   row   = wsi + 2048 + NPAD;          // [N+1]
    int*   csr   = wsi + 2048 + 2 * NPAD;      // [E]  (binned & csr share this)
    unsigned int* binned = (unsigned int*)csr;
    float* hh    = wsf + 2048 + 2 * NPAD + N_EDGES;    // [N*16]
    float* agg1  = hh   + (size_t)N_NODES * 16;        // [N*16]
    float* hh2   = agg1 + (size_t)N_NODES * 16;        // [N*16]
    float* agg2  = hh2  + (size_t)N_NODES * 16;        // [N*16]
    unsigned short* w1t = (unsigned short*)(agg2 + (size_t)N_NODES * 16);  // [16*512] bf16

    const int NB = (N_NODES + 255) / 256;      // 391
    const int GB = N_NODES / 16;               // 6250 (exact)
    const int MB = (N_NODES + 63) / 64;        // 1563 (MFMA gemm blocks)

    hipMemsetAsync(gcnt, 0, NBKT * sizeof(int), stream);
    bin_count_kernel <<<SBLK, 1024, 0, stream>>>(dst, gcnt);
    bucket_scan_kernel<<<1, 512, 0, stream>>>(gcnt, bbase, gcur);
    bin_scatter_kernel<<<SBLK, 1024, 0, stream>>>(src, dst, gcur, binned);
    csr_bucket_kernel<<<NBKT, 1024, 0, stream>>>(binned, bbase, row, csr, dinv);
    w1prep_kernel<<<32, 256, 0, stream>>>(W1, w1t);
    gemm1_kernel<<<MB, 256, 0, stream>>>(x, w1t, b1, dinv, hh, agg1);
    pull_kernel<<<GB, 256, 0, stream>>>(hh, dinv, row, csr, agg1);
    layer2_kernel<<<NB, 256, 0, stream>>>(agg1, W2, b2, dinv, hh2, agg2);
    pull_kernel<<<GB, 256, 0, stream>>>(hh2, dinv, row, csr, agg2);
    lsm_kernel<<<NB, 256, 0, stream>>>(agg2, out);
}

// Round 6
// 483.031 us; speedup vs baseline: 2.2272x; 1.0206x over previous
//
#include <hip/hip_runtime.h>
#include <hip/hip_bf16.h>
#include <math.h>

// Problem constants (fixed by the reference file).
constexpr int N_NODES = 100000;
constexpr int N_EDGES = 3200000;
constexpr int F_IN    = 512;
constexpr int HID     = 16;   // HIDDEN == N_CLASSES == 16

constexpr int NPAD = 100352;  // N_NODES rounded up (words)

// Binning parameters: bucket = dst >> 8 (256 nodes/bucket)
constexpr int B_BITS = 8;
constexpr int NPB    = 1 << B_BITS;                    // 256 nodes per bucket
constexpr int NBKT   = (N_NODES + NPB - 1) / NPB;      // 391 buckets
constexpr int SBLK   = 400;                            // scatter blocks
constexpr int CHUNK  = N_EDGES / SBLK;                 // 8000 edges/block (exact)
constexpr int MAX_BKT_E = 12288;  // mean 8184, sd ~90; 48KB LDS

typedef float f32x4 __attribute__((ext_vector_type(4)));
typedef short bfrag8 __attribute__((ext_vector_type(8)));   // 8 bf16 (4 VGPRs)

__device__ __forceinline__ unsigned short f2bf_rne(float f) {
    unsigned int u = __float_as_uint(f);
    u += 0x7FFFu + ((u >> 16) & 1u);   // round-to-nearest-even
    return (unsigned short)(u >> 16);
}
__device__ __forceinline__ float bf2f(unsigned short u) {
    return __uint_as_float((unsigned int)u << 16);
}

// ---------------------------------------------------------------------------
// K1: per-block LDS histogram of dst-buckets -> global bucket counts.
__global__ __launch_bounds__(1024) void bin_count_kernel(const int* __restrict__ dst,
                                                         int* __restrict__ gcnt) {
    __shared__ int cnt[NBKT];
    const int tid = threadIdx.x;
    for (int t = tid; t < NBKT; t += 1024) cnt[t] = 0;
    __syncthreads();
    const int base = blockIdx.x * CHUNK;
    for (int i = tid; i < CHUNK; i += 1024)
        atomicAdd(&cnt[dst[base + i] >> B_BITS], 1);
    __syncthreads();
    for (int t = tid; t < NBKT; t += 1024)
        if (cnt[t]) atomicAdd(&gcnt[t], cnt[t]);
}

// ---------------------------------------------------------------------------
// K2: scan 391 bucket counts -> bucket base offsets (+ cursor copy). 1 block.
__global__ __launch_bounds__(512) void bucket_scan_kernel(const int* __restrict__ gcnt,
                                                          int* __restrict__ bbase,
                                                          int* __restrict__ gcur) {
    __shared__ int s[512];
    const int tid = threadIdx.x;
    s[tid] = (tid < NBKT) ? gcnt[tid] : 0;
    __syncthreads();
    for (int off = 1; off < 512; off <<= 1) {
        int v = (tid >= off) ? s[tid - off] : 0;
        __syncthreads();
        s[tid] += v;
        __syncthreads();
    }
    int excl = (tid == 0) ? 0 : s[tid - 1];
    if (tid <= NBKT) bbase[tid] = excl;
    if (tid <  NBKT) gcur[tid]  = excl;
}

// ---------------------------------------------------------------------------
// K3: scatter edges into bucket-grouped array (writes L2-localized),
// packed as (local_dst<<24 | src).
__global__ __launch_bounds__(1024) void bin_scatter_kernel(const int* __restrict__ src,
                                                           const int* __restrict__ dst,
                                                           int* __restrict__ gcur,
                                                           unsigned int* __restrict__ binned) {
    __shared__ int cnt[NBKT];
    __shared__ int cur[NBKT];
    const int tid = threadIdx.x;
    for (int t = tid; t < NBKT; t += 1024) cnt[t] = 0;
    __syncthreads();
    const int base = blockIdx.x * CHUNK;
    for (int i = tid; i < CHUNK; i += 1024)
        atomicAdd(&cnt[dst[base + i] >> B_BITS], 1);
    __syncthreads();
    for (int t = tid; t < NBKT; t += 1024)
        cur[t] = cnt[t] ? atomicAdd(&gcur[t], cnt[t]) : 0;
    __syncthreads();
    for (int i = tid; i < CHUNK; i += 1024) {
        int d = dst[base + i];
        int b = d >> B_BITS;
        int pos = atomicAdd(&cur[b], 1);
        binned[pos] = ((unsigned)(d & (NPB - 1)) << 24) | (unsigned)src[base + i];
    }
}

// ---------------------------------------------------------------------------
// K4: one block per bucket: LDS-local CSR build + deg/dinv/row emission.
__global__ __launch_bounds__(1024) void csr_bucket_kernel(const unsigned int* __restrict__ binned,
                                                          const int* __restrict__ bbase,
                                                          int* __restrict__ row,
                                                          int* __restrict__ csr,
                                                          float* __restrict__ dinv) {
    __shared__ unsigned int eb[MAX_BKT_E];
    __shared__ int deg[NPB];
    __shared__ int pre[NPB];
    __shared__ int cur[NPB];
    const int tid = threadIdx.x;
    const int b = blockIdx.x;
    const int e0 = bbase[b];
    int ne = bbase[b + 1] - e0;
    if (ne > MAX_BKT_E) ne = MAX_BKT_E;  // safety (statistically impossible)

    if (tid < NPB) deg[tid] = 0;
    for (int i = tid; i < ne; i += 1024) eb[i] = binned[e0 + i];
    __syncthreads();
    for (int i = tid; i < ne; i += 1024)
        atomicAdd(&deg[eb[i] >> 24], 1);
    __syncthreads();
    if (tid < NPB) pre[tid] = deg[tid];
    __syncthreads();
    for (int off = 1; off < NPB; off <<= 1) {
        int v = 0;
        if (tid < NPB && tid >= off) v = pre[tid - off];
        __syncthreads();
        if (tid < NPB) pre[tid] += v;
        __syncthreads();
    }
    if (tid < NPB) {
        int excl = (tid == 0) ? 0 : pre[tid - 1];
        int g = e0 + excl;
        cur[tid] = g;
        int node = b * NPB + tid;
        if (node < N_NODES) {
            row[node] = g;
            dinv[node] = rsqrtf((float)deg[tid] + 1.0f);
        }
    }
    if (b == 0 && tid == 0) row[N_NODES] = N_EDGES;
    __syncthreads();
    for (int i = tid; i < ne; i += 1024) {
        unsigned int v = eb[i];
        int pos = atomicAdd(&cur[v >> 24], 1);
        csr[pos] = (int)(v & 0xFFFFFFu);
    }
}

// ---------------------------------------------------------------------------
// K5a: W1 prep — fp32 [k][n] -> bf16 transposed w1t[n][k]. Tiny.
__global__ __launch_bounds__(256) void w1prep_kernel(const float* __restrict__ W1,
                                                     unsigned short* __restrict__ w1t) {
    int i = blockIdx.x * 256 + threadIdx.x;
    if (i < F_IN * HID) {
        int k = i >> 4, n = i & 15;
        w1t[n * F_IN + k] = f2bf_rne(W1[i]);
    }
}

// ---------------------------------------------------------------------------
// K5: GEMM1 via MFMA bf16, NO LDS, NO barrier (R5 post-mortem: staged-LDS
// versions stall on the stage->compute barrier drain at 2 blocks/CU).
// Each wave owns a 16-node tile; lane (m=lane&15, quad=lane>>4) loads its
// A-frag (8 contiguous floats at x[node0+m][t*32+quad*8]) directly from
// global — a wave covers 16 rows x 128 B, fully coalesced — converts to
// bf16 in-register, and MFMAs. B-frags (W1^T bf16, L2-hot) preloaded.
// Writes hh_bf (bf16, h*dinv) and aggs1 (fp32, h*dinv^2 + b1).
__global__ __launch_bounds__(256) void gemm1_kernel(const float* __restrict__ x,
                                                    const unsigned short* __restrict__ w1t,
                                                    const float* __restrict__ b1,
                                                    const float* __restrict__ dinv,
                                                    unsigned short* __restrict__ hh_bf,
                                                    float* __restrict__ aggs1) {
    const int tid  = threadIdx.x;
    const int lane = tid & 63;
    const int wv   = tid >> 6;
    const int m    = lane & 15;
    const int quad = lane >> 4;
    const int node0 = blockIdx.x * 64 + wv * 16;   // this wave's 16-node tile

    int gm = node0 + m; if (gm >= N_NODES) gm = N_NODES - 1;  // clamp loads
    const float* arow = x + (size_t)gm * F_IN + quad * 8;

    // preload all 16 B-frags (16 KB table, L2-hot)
    bfrag8 bfr[16];
    const unsigned short* wbase = w1t + m * F_IN + quad * 8;
    #pragma unroll
    for (int t = 0; t < 16; ++t)
        bfr[t] = *(const bfrag8*)(wbase + t * 32);

    f32x4 acc = {0.f, 0.f, 0.f, 0.f};
    #pragma unroll 4
    for (int t = 0; t < 16; ++t) {
        float4 lo = *(const float4*)(arow + t * 32);
        float4 hi = *(const float4*)(arow + t * 32 + 4);
        bfrag8 afr;
        afr[0] = (short)f2bf_rne(lo.x); afr[1] = (short)f2bf_rne(lo.y);
        afr[2] = (short)f2bf_rne(lo.z); afr[3] = (short)f2bf_rne(lo.w);
        afr[4] = (short)f2bf_rne(hi.x); afr[5] = (short)f2bf_rne(hi.y);
        afr[6] = (short)f2bf_rne(hi.z); afr[7] = (short)f2bf_rne(hi.w);
        acc = __builtin_amdgcn_mfma_f32_16x16x32_bf16(afr, bfr[t], acc, 0, 0, 0);
    }

    // epilogue: D[row=quad*4+r][col=m] (verified R5 mapping)
    const float b1j = b1[m];
    #pragma unroll
    for (int r = 0; r < 4; ++r) {
        int gn = node0 + quad * 4 + r;
        if (gn < N_NODES) {
            float dv = dinv[gn];
            float hv = acc[r] * dv;
            size_t o = (size_t)gn * 16 + m;
            hh_bf[o] = f2bf_rne(hv);
            aggs1[o] = hv * dv + b1j;
        }
    }
}

// ---------------------------------------------------------------------------
// K6: pull1 + relu + layer2 fused. 16 lanes per node (j=feature), x4 unroll.
// Gathers are bf16 (32 B/node-row -> table 3.2 MB, fits per-XCD L2).
// After aggregation, the node's 16 features live in the 16-lane group:
// 16x16 GEMM with W2 via __shfl broadcast. Writes hh2_bf and aggs2.
__global__ __launch_bounds__(256) void pull1_kernel(const unsigned short* __restrict__ hh_bf,
                                                    const float* __restrict__ aggs1,
                                                    const float* __restrict__ dinv,
                                                    const int* __restrict__ row,
                                                    const int* __restrict__ csr,
                                                    const float* __restrict__ W2,
                                                    const float* __restrict__ b2,
                                                    unsigned short* __restrict__ hh2_bf,
                                                    float* __restrict__ aggs2) {
    __shared__ float w2s[256];
    __shared__ float b2s[16];
    const int tid = threadIdx.x;
    w2s[tid] = W2[tid];
    if (tid < 16) b2s[tid] = b2[tid];
    __syncthreads();

    int t = blockIdx.x * 256 + tid;          // grid covers N*16 exactly
    int node = t >> 4;
    int j = t & 15;
    int p = row[node], end = row[node + 1];
    float a0 = 0.f, a1 = 0.f, a2 = 0.f, a3 = 0.f;
    for (; p + 4 <= end; p += 4) {
        int s0 = csr[p], s1 = csr[p + 1], s2 = csr[p + 2], s3 = csr[p + 3];
        a0 += bf2f(hh_bf[(s0 << 4) + j]);
        a1 += bf2f(hh_bf[(s1 << 4) + j]);
        a2 += bf2f(hh_bf[(s2 << 4) + j]);
        a3 += bf2f(hh_bf[(s3 << 4) + j]);
    }
    for (; p < end; ++p) a0 += bf2f(hh_bf[(csr[p] << 4) + j]);
    float dv = dinv[node];
    float aj = aggs1[(node << 4) + j] + dv * ((a0 + a1) + (a2 + a3));
    float vj = fmaxf(aj, 0.f);               // relu(h1)

    // h2[j] = sum_k v[k] * W2[k][j] — broadcast v across the 16-lane group
    float h2 = 0.f;
    #pragma unroll
    for (int k = 0; k < 16; ++k) {
        float vk = __shfl(vj, k, 16);
        h2 += vk * w2s[k * 16 + j];
    }
    size_t o = (size_t)node * 16 + j;
    float hv = h2 * dv;
    hh2_bf[o] = f2bf_rne(hv);
    aggs2[o] = hv * dv + b2s[j];
}

// ---------------------------------------------------------------------------
// K7: pull2 + log_softmax fused. Same gather structure; then shfl_xor
// max/sum reductions within the 16-lane group and direct output write.
__global__ __launch_bounds__(256) void pull2_kernel(const unsigned short* __restrict__ hh2_bf,
                                                    const float* __restrict__ aggs2,
                                                    const float* __restrict__ dinv,
                                                    const int* __restrict__ row,
                                                    const int* __restrict__ csr,
                                                    float* __restrict__ out) {
    int t = blockIdx.x * 256 + threadIdx.x;
    int node = t >> 4;
    int j = t & 15;
    int p = row[node], end = row[node + 1];
    float a0 = 0.f, a1 = 0.f, a2 = 0.f, a3 = 0.f;
    for (; p + 4 <= end; p += 4) {
        int s0 = csr[p], s1 = csr[p + 1], s2 = csr[p + 2], s3 = csr[p + 3];
        a0 += bf2f(hh2_bf[(s0 << 4) + j]);
        a1 += bf2f(hh2_bf[(s1 << 4) + j]);
        a2 += bf2f(hh2_bf[(s2 << 4) + j]);
        a3 += bf2f(hh2_bf[(s3 << 4) + j]);
    }
    for (; p < end; ++p) a0 += bf2f(hh2_bf[(csr[p] << 4) + j]);
    float oj = aggs2[(node << 4) + j] + dinv[node] * ((a0 + a1) + (a2 + a3));

    // log_softmax over the 16-lane group
    float mx = oj;
    mx = fmaxf(mx, __shfl_xor(mx, 1));
    mx = fmaxf(mx, __shfl_xor(mx, 2));
    mx = fmaxf(mx, __shfl_xor(mx, 4));
    mx = fmaxf(mx, __shfl_xor(mx, 8));
    float e = expf(oj - mx);
    float s = e;
    s += __shfl_xor(s, 1);
    s += __shfl_xor(s, 2);
    s += __shfl_xor(s, 4);
    s += __shfl_xor(s, 8);
    out[(size_t)node * 16 + j] = oj - mx - logf(s);
}

// ---------------------------------------------------------------------------
extern "C" void kernel_launch(void* const* d_in, const int* in_sizes, int n_in,
                              void* d_out, int out_size, void* d_ws, size_t ws_size,
                              hipStream_t stream) {
    const float* x    = (const float*)d_in[0];
    const float* W1   = (const float*)d_in[1];
    const float* b1   = (const float*)d_in[2];
    const float* W2   = (const float*)d_in[3];
    const float* b2   = (const float*)d_in[4];
    const int*   ei   = (const int*)d_in[5];
    const int*   src  = ei;             // edge_index[0]
    const int*   dst  = ei + N_EDGES;   // edge_index[1]
    float* out = (float*)d_out;

    // workspace layout (4-byte words); total ~33 MB
    int*   wsi  = (int*)d_ws;
    float* wsf  = (float*)d_ws;
    int*   gcnt  = wsi;                        // [NBKT]
    int*   bbase = wsi + 512;                  // [NBKT+1]
    int*   gcur  = wsi + 1024;                 // [NBKT]
    float* dinv  = wsf + 2048;                 // [NPAD]
    int*   row   = wsi + 2048 + NPAD;          // [N+1]
    int*   csr   = wsi + 2048 + 2 * NPAD;      // [E]  (binned & csr share this)
    unsigned int* binned = (unsigned int*)csr;
    const size_t off0 = 2048 + 2 * (size_t)NPAD + N_EDGES;           // words
    unsigned short* hh_bf  = (unsigned short*)(wsi + off0);          // [N*16] bf16
    float*          aggs1  = wsf + off0 + 800000;                    // [N*16]
    unsigned short* hh2_bf = (unsigned short*)(wsi + off0 + 2400000);// [N*16] bf16
    float*          aggs2  = wsf + off0 + 3200000;                   // [N*16]
    unsigned short* w1t    = (unsigned short*)(wsi + off0 + 4800000);// [16*512] bf16

    const int GB = N_NODES / 16;               // 6250 (N*16 / 256 exact)
    const int MB = (N_NODES + 63) / 64;        // 1563 (MFMA gemm blocks)

    hipMemsetAsync(gcnt, 0, NBKT * sizeof(int), stream);
    bin_count_kernel <<<SBLK, 1024, 0, stream>>>(dst, gcnt);
    bucket_scan_kernel<<<1, 512, 0, stream>>>(gcnt, bbase, gcur);
    bin_scatter_kernel<<<SBLK, 1024, 0, stream>>>(src, dst, gcur, binned);
    csr_bucket_kernel<<<NBKT, 1024, 0, stream>>>(binned, bbase, row, csr, dinv);
    w1prep_kernel<<<32, 256, 0, stream>>>(W1, w1t);
    gemm1_kernel<<<MB, 256, 0, stream>>>(x, w1t, b1, dinv, hh_bf, aggs1);
    pull1_kernel<<<GB, 256, 0, stream>>>(hh_bf, aggs1, dinv, row, csr, W2, b2, hh2_bf, aggs2);
    pull2_kernel<<<GB, 256, 0, stream>>>(hh2_bf, aggs2, dinv, row, csr, out);
}